// Round 18
// baseline (980.533 us; speedup 1.0000x reference)
//
#include <hip/hip_runtime.h>
#include <hip/hip_fp16.h>
#include <math.h>

#define NUSERS 100000
#define NITEMS 50000
#define BATCH  64
#define ORDER  8
#define BSHIFT 9                                   // 512 rows per bucket
#define BROWS  (1 << BSHIFT)
#define NBUCKU ((NUSERS + BROWS - 1) >> BSHIFT)    // 196
#define NBUCKI ((NITEMS + BROWS - 1) >> BSHIFT)    // 98
#define CAPU 16384
#define CAPI 24576
#define S1_BLOCKS 512
#define NREP 4
#define RPW 8                                      // rows per wave (both SpMMs)

// ---------------------------------------------------------------------------
// R14/R17 structure (best: 768us): padded rows (dummy->zero row), fixed-cap
// buckets, inlined scales, fp16 8B/lane gathers, 4 rows/wave both sides.
// R18: 8 rows/wave -- SpMMs are latency-MLP-bound (0.14 lines/cyc/CU with 16
// outstanding gathers/wave); doubling in-flight loads per wave attacks the
// binding resource directly. Per-row numerics bit-identical.
// ---------------------------------------------------------------------------

struct __align__(8) Half4 { __half2 a, b; };
struct Coeffs { float v[ORDER + 1]; };

#define SLOT ((size_t)(NITEMS + 1) * BATCH)        // fp16 tau slot incl. zero row

__device__ __forceinline__ void acc_pk(float4& acc, Half4 v0, Half4 v1,
                                       Half4 v2, Half4 v3) {
    __half2 sa = __hadd2(__hadd2(v0.a, v1.a), __hadd2(v2.a, v3.a));
    __half2 sb = __hadd2(__hadd2(v0.b, v1.b), __hadd2(v2.b, v3.b));
    float2 fa = __half22float2(sa);
    float2 fb = __half22float2(sb);
    acc.x += fa.x; acc.y += fa.y; acc.z += fb.x; acc.w += fb.y;
}

__device__ __forceinline__ Half4 to_h4(float x, float y, float z, float w) {
    Half4 h;
    h.a = __floats2half2_rn(x, y);
    h.b = __floats2half2_rn(z, w);
    return h;
}

// ---------------------------------------------------------------------------
// CSR build (R14)
// ---------------------------------------------------------------------------
__global__ void init_bcur(int* __restrict__ bcurU, int* __restrict__ bcurI) {
    int t = blockIdx.x * blockDim.x + threadIdx.x;
    if (t < NBUCKU) bcurU[t] = t * CAPU;
    if (t < NBUCKI) bcurI[t] = t * CAPI;
}

__global__ void zero_pads(__half* __restrict__ tauHall, __half* __restrict__ ybuf) {
    int t = threadIdx.x;
    for (int k = 0; k <= ORDER; ++k)
        if (t < BATCH) tauHall[(size_t)k * SLOT + (size_t)NITEMS * BATCH + t] = __float2half(0.f);
    if (t < BATCH) ybuf[(size_t)NUSERS * BATCH + t] = __float2half(0.f);
}

__global__ void scatter1(const int* __restrict__ row, const int* __restrict__ col,
                         int* __restrict__ bcurU, int* __restrict__ bcurI,
                         int* __restrict__ stU, int* __restrict__ stI, int nnz) {
    __shared__ int cU[NREP][NBUCKU];
    __shared__ int cI[NREP][NBUCKI];
    const int chunk = (nnz + S1_BLOCKS - 1) / S1_BLOCKS;
    const int b0 = blockIdx.x * chunk;
    const int e0 = min(b0 + chunk, nnz);
    const int sw = threadIdx.x >> 6;
    for (int t = threadIdx.x; t < NREP * NBUCKU; t += blockDim.x) (&cU[0][0])[t] = 0;
    for (int t = threadIdx.x; t < NREP * NBUCKI; t += blockDim.x) (&cI[0][0])[t] = 0;
    __syncthreads();
    for (int i = b0 + threadIdx.x; i < e0; i += blockDim.x) {
        atomicAdd(&cU[sw][row[i] >> BSHIFT], 1);
        atomicAdd(&cI[sw][col[i] >> BSHIFT], 1);
    }
    __syncthreads();
    for (int t = threadIdx.x; t < NBUCKU; t += blockDim.x) {
        int c0 = cU[0][t], c1 = cU[1][t], c2 = cU[2][t], c3 = cU[3][t];
        int tot = c0 + c1 + c2 + c3;
        int base = (tot > 0) ? atomicAdd(&bcurU[t], tot) : 0;
        cU[0][t] = base;
        cU[1][t] = base + c0;
        cU[2][t] = base + c0 + c1;
        cU[3][t] = base + c0 + c1 + c2;
    }
    for (int t = threadIdx.x; t < NBUCKI; t += blockDim.x) {
        int c0 = cI[0][t], c1 = cI[1][t], c2 = cI[2][t], c3 = cI[3][t];
        int tot = c0 + c1 + c2 + c3;
        int base = (tot > 0) ? atomicAdd(&bcurI[t], tot) : 0;
        cI[0][t] = base;
        cI[1][t] = base + c0;
        cI[2][t] = base + c0 + c1;
        cI[3][t] = base + c0 + c1 + c2;
    }
    __syncthreads();
    for (int i = b0 + threadIdx.x; i < e0; i += blockDim.x) {
        int r = row[i], c = col[i];
        int pu = atomicAdd(&cU[sw][r >> BSHIFT], 1);
        stU[pu] = ((r & (BROWS - 1)) << 17) | c;
        int pi = atomicAdd(&cI[sw][c >> BSHIFT], 1);
        stI[pi] = ((c & (BROWS - 1)) << 17) | r;
    }
}

__global__ void scatter2(const int* __restrict__ bcur, const int* __restrict__ st,
                         int* __restrict__ ptr, int* __restrict__ degOut,
                         int* __restrict__ outIdx, int nrows, int cap, int dummyIdx) {
    __shared__ int deg[BROWS];
    __shared__ int ps[256];
    __shared__ int cur[BROWS];
    __shared__ int rs[BROWS];
    const int rbase = blockIdx.x << BSHIFT;
    const int nr = min(BROWS, nrows - rbase);
    const int lo = blockIdx.x * cap;
    const int hi = bcur[blockIdx.x];
    const int t = threadIdx.x;
    deg[2 * t] = 0;
    deg[2 * t + 1] = 0;
    __syncthreads();
    for (int j = lo + t; j < hi; j += 256)
        atomicAdd(&deg[st[j] >> 17], 1);
    __syncthreads();
    int a = deg[2 * t];
    int b = deg[2 * t + 1];
    int pa = (a + 15) & ~15;
    int pb = (b + 15) & ~15;
    ps[t] = pa + pb;
    __syncthreads();
    for (int off = 1; off < 256; off <<= 1) {
        int u = (t >= off) ? ps[t - off] : 0;
        __syncthreads();
        ps[t] += u;
        __syncthreads();
    }
    int excl = (t > 0) ? ps[t - 1] : 0;
    int p0 = lo + excl;
    int p1 = p0 + pa;
    rs[2 * t] = p0;
    rs[2 * t + 1] = p1;
    cur[2 * t] = p0;
    cur[2 * t + 1] = p1;
    if (2 * t < nr)     { ptr[rbase + 2 * t] = p0;     degOut[rbase + 2 * t] = a; }
    if (2 * t + 1 < nr) { ptr[rbase + 2 * t + 1] = p1; degOut[rbase + 2 * t + 1] = b; }
    __syncthreads();
    for (int j = lo + t; j < hi; j += 256) {
        int v = st[j];
        int p = atomicAdd(&cur[v >> 17], 1);
        outIdx[p] = v & 0x1FFFF;
    }
    __syncthreads();
    for (int i = t; i < nr; i += 256) {
        int endReal = cur[i];
        int endPad  = rs[i] + ((deg[i] + 15) & ~15);
        for (int j = endReal; j < endPad; ++j) outIdx[j] = dummyIdx;
    }
}

// ---------------------------------------------------------------------------
// transposes (R14)
// ---------------------------------------------------------------------------
__global__ void transpose_scale_k(const float* __restrict__ in,
                                  const int* __restrict__ ideg,
                                  float* __restrict__ out,
                                  __half* __restrict__ outH) {
    __shared__ float tile[32][33];
    const int cb = blockIdx.x * 32;
    const int rb = blockIdx.y * 32;
    for (int i = threadIdx.y; i < 32; i += 8) {
        int r = rb + i, c = cb + threadIdx.x;
        if (r < BATCH && c < NITEMS) tile[i][threadIdx.x] = in[(size_t)r * NITEMS + c];
    }
    __syncthreads();
    for (int i = threadIdx.y; i < 32; i += 8) {
        int c = cb + i, r = rb + threadIdx.x;
        if (c < NITEMS && r < BATCH) {
            int d = ideg[c];
            float dis = (d > 0) ? rsqrtf((float)d) : 0.0f;
            float v = dis * tile[threadIdx.x][i];
            out[(size_t)c * BATCH + r] = v;
            outH[(size_t)c * BATCH + r] = __float2half(v);
        }
    }
}

__global__ void transpose_out_k(const __half* __restrict__ tauHall,
                                const float* __restrict__ signal,
                                const int* __restrict__ ideg, float csum, Coeffs cf,
                                float* __restrict__ out) {
    __shared__ float tile[32][33];
    const int cb = blockIdx.x * 32;
    const int rb = blockIdx.y * 32;
    for (int i = threadIdx.y; i < 32; i += 8) {
        int r = rb + i, c = cb + threadIdx.x;
        if (r < NITEMS && c < BATCH) {
            size_t base = (size_t)r * BATCH + c;
            float s = 0.f;
            #pragma unroll
            for (int k = 0; k <= ORDER; ++k)
                s += cf.v[k] * __half2float(tauHall[(size_t)k * SLOT + base]);
            tile[i][threadIdx.x] = s;
        }
    }
    __syncthreads();
    for (int i = threadIdx.y; i < 32; i += 8) {
        int c = cb + i, r = rb + threadIdx.x;
        if (c < BATCH && r < NITEMS) {
            int d = ideg[r];
            float v = (d > 0) ? sqrtf((float)d) * tile[threadIdx.x][i]
                              : csum * signal[(size_t)c * NITEMS + r];
            out[(size_t)c * NITEMS + r] = v;
        }
    }
}

// ---------------------------------------------------------------------------
// 8-row gather core: padded rows, exactly n=(deg+15)>>4 iters; 32 gathers in
// flight per wave (was 16). Per-row edge->slot mapping unchanged.
// ---------------------------------------------------------------------------
__device__ __forceinline__ void gather8_p(const int* __restrict__ idx,
                                          const Half4* __restrict__ x,
                                          const int* b, const int* n,
                                          int sub, int bh, float4* a) {
    int j[RPW];
    int nmax = 0;
    #pragma unroll
    for (int q = 0; q < RPW; ++q) {
        j[q] = b[q] + (sub << 2);
        nmax = max(nmax, n[q]);
    }
    for (int it = 0; it < nmax; ++it) {
        #pragma unroll
        for (int q = 0; q < RPW; ++q) {
            if (it < n[q]) {
                int i0 = idx[j[q]], i1 = idx[j[q] + 1];
                int i2 = idx[j[q] + 2], i3 = idx[j[q] + 3];
                Half4 v0 = x[(size_t)i0 * 16 + bh];
                Half4 v1 = x[(size_t)i1 * 16 + bh];
                Half4 v2 = x[(size_t)i2 * 16 + bh];
                Half4 v3 = x[(size_t)i3 * 16 + bh];
                acc_pk(a[q], v0, v1, v2, v3);
                j[q] += 16;
            }
        }
    }
    #pragma unroll
    for (int q = 0; q < RPW; ++q) {
        a[q].x += __shfl_xor(a[q].x, 16); a[q].y += __shfl_xor(a[q].y, 16);
        a[q].z += __shfl_xor(a[q].z, 16); a[q].w += __shfl_xor(a[q].w, 16);
        a[q].x += __shfl_xor(a[q].x, 32); a[q].y += __shfl_xor(a[q].y, 32);
        a[q].z += __shfl_xor(a[q].z, 32); a[q].w += __shfl_xor(a[q].w, 32);
    }
}

// user side (8 rows/wave, padded): y[u] = (1/deg_u) * sum tauH[col]
__global__ void spmm_user(const int* __restrict__ ptr, const int* __restrict__ deg,
                          const int* __restrict__ idx,
                          const Half4* __restrict__ tauH, Half4* __restrict__ y) {
    const int lane = threadIdx.x & 63;
    const int w = (blockIdx.x * blockDim.x + threadIdx.x) >> 6;
    const int H = NUSERS / RPW;
    if (w >= H) return;
    int r[RPW];
    #pragma unroll
    for (int q = 0; q < RPW; ++q) r[q] = w + q * H;
    const int sub = lane >> 4;
    const int bh  = lane & 15;
    int b[RPW], d[RPW], n[RPW];
    #pragma unroll
    for (int q = 0; q < RPW; ++q) {
        b[q] = ptr[r[q]];
        d[q] = deg[r[q]];
        n[q] = (d[q] + 15) >> 4;
    }
    float4 a[RPW] = {};
    gather8_p(idx, tauH, b, n, sub, bh, a);
    if (sub == 0) {
        #pragma unroll
        for (int q = 0; q < RPW; ++q) {
            float s = (d[q] > 0) ? 1.0f / (float)d[q] : 0.0f;
            y[(size_t)r[q] * 16 + bh] = to_h4(s * a[q].x, s * a[q].y, s * a[q].z, s * a[q].w);
        }
    }
}

// item, first step: tau1 = tau0 - (2/deg)*z ; write fp32 + fp16
__global__ void spmm_item_first(const int* __restrict__ ptr, const int* __restrict__ deg,
                                const int* __restrict__ idx, const Half4* __restrict__ y,
                                const float* __restrict__ tau0, float* __restrict__ tau1,
                                Half4* __restrict__ tauH1) {
    const int lane = threadIdx.x & 63;
    const int w = (blockIdx.x * blockDim.x + threadIdx.x) >> 6;
    const int H = NITEMS / RPW;
    if (w >= H) return;
    int r[RPW];
    #pragma unroll
    for (int q = 0; q < RPW; ++q) r[q] = w + q * H;
    const int sub = lane >> 4;
    const int bh  = lane & 15;
    int b[RPW], d[RPW], n[RPW];
    #pragma unroll
    for (int q = 0; q < RPW; ++q) {
        b[q] = ptr[r[q]];
        d[q] = deg[r[q]];
        n[q] = (d[q] + 15) >> 4;
    }
    float4 a[RPW] = {};
    gather8_p(idx, y, b, n, sub, bh, a);
    if (sub == 0) {
        #pragma unroll
        for (int q = 0; q < RPW; ++q) {
            float inv = (d[q] > 0) ? 1.0f / (float)d[q] : 0.0f;
            float s2 = 2.0f * inv;
            size_t base = (size_t)r[q] * BATCH + (bh << 2);
            float4 t0v = *(const float4*)&tau0[base];
            float4 t;
            t.x = t0v.x - s2 * a[q].x; t.y = t0v.y - s2 * a[q].y;
            t.z = t0v.z - s2 * a[q].z; t.w = t0v.w - s2 * a[q].w;
            *(float4*)&tau1[base] = t;
            tauH1[(size_t)r[q] * 16 + bh] = to_h4(t.x, t.y, t.z, t.w);
        }
    }
}

// item, general step: t2 = 2*t1 - (4/deg)*z - t0 ; write fp32 + fp16
__global__ void spmm_item_k(const int* __restrict__ ptr, const int* __restrict__ deg,
                            const int* __restrict__ idx, const Half4* __restrict__ y,
                            const float* __restrict__ tau1, float* __restrict__ tau0,
                            Half4* __restrict__ tauHk) {
    const int lane = threadIdx.x & 63;
    const int w = (blockIdx.x * blockDim.x + threadIdx.x) >> 6;
    const int H = NITEMS / RPW;
    if (w >= H) return;
    int r[RPW];
    #pragma unroll
    for (int q = 0; q < RPW; ++q) r[q] = w + q * H;
    const int sub = lane >> 4;
    const int bh  = lane & 15;
    int b[RPW], d[RPW], n[RPW];
    #pragma unroll
    for (int q = 0; q < RPW; ++q) {
        b[q] = ptr[r[q]];
        d[q] = deg[r[q]];
        n[q] = (d[q] + 15) >> 4;
    }
    float4 a[RPW] = {};
    gather8_p(idx, y, b, n, sub, bh, a);
    if (sub == 0) {
        #pragma unroll
        for (int q = 0; q < RPW; ++q) {
            float inv = (d[q] > 0) ? 1.0f / (float)d[q] : 0.0f;
            float s4 = 4.0f * inv;
            size_t base = (size_t)r[q] * BATCH + (bh << 2);
            float4 t1v = *(const float4*)&tau1[base];
            float4 t0v = *(const float4*)&tau0[base];
            float4 t2;
            t2.x = 2.0f * t1v.x - s4 * a[q].x - t0v.x;
            t2.y = 2.0f * t1v.y - s4 * a[q].y - t0v.y;
            t2.z = 2.0f * t1v.z - s4 * a[q].z - t0v.z;
            t2.w = 2.0f * t1v.w - s4 * a[q].w - t0v.w;
            *(float4*)&tau0[base] = t2;
            tauHk[(size_t)r[q] * 16 + bh] = to_h4(t2.x, t2.y, t2.z, t2.w);
        }
    }
}

// ---------------------------------------------------------------------------
// Host-side exact replica of reference cheby_coeffs
// ---------------------------------------------------------------------------
static void cheby_coeffs_host(float* c) {
    const int order = ORDER, flatness = 2;
    const double PI = 3.14159265358979323846;
    double tgt[ORDER + 1], nodes[ORDER + 1];
    for (int x = 0; x <= order; ++x) {
        double xv = cos((double)(order - x) / order * PI);
        xv = nearbyint(xv * 1000.0) / 1000.0;
        double t = (xv < 0.0) ? pow(-xv, (double)flatness) * 0.5 + 0.5
                              : pow(xv, (double)flatness) * (-0.5) + 0.5;
        tgt[x] = nearbyint(t * 1000.0) / 1000.0;
    }
    for (int k = 1; k <= order + 1; ++k)
        nodes[k - 1] = cos((order + 1 + 0.5 - k) / (double)(order + 1) * PI);

    double prev[ORDER + 1], cur[ORDER + 1], nxt[ORDER + 1];
    double sums[ORDER + 1];
    double s0 = 0, s1 = 0;
    for (int i = 0; i <= order; ++i) {
        prev[i] = tgt[i];
        cur[i]  = nodes[i] * tgt[i];
        s0 += prev[i];
        s1 += cur[i];
    }
    sums[0] = s0; sums[1] = s1;
    for (int j = 2; j <= order; ++j) {
        double s = 0;
        for (int i = 0; i <= order; ++i) {
            nxt[i] = nodes[i] * cur[i] * 2.0 - prev[i];
            s += nxt[i];
        }
        sums[j] = s;
        for (int i = 0; i <= order; ++i) { prev[i] = cur[i]; cur[i] = nxt[i]; }
    }
    for (int j = 0; j <= order; ++j)
        c[j] = (float)(sums[j] * (2.0 / (order + 1)));
    c[0] *= 0.5f;
}

extern "C" void kernel_launch(void* const* d_in, const int* in_sizes, int n_in,
                              void* d_out, int out_size, void* d_ws, size_t ws_size,
                              hipStream_t stream) {
    const float* signal = (const float*)d_in[0];   // [BATCH, NITEMS]
    const int*   row    = (const int*)d_in[2];     // [NNZ] -> users
    const int*   col    = (const int*)d_in[3];     // [NNZ] -> items
    const int nnz = in_sizes[1];

    char* wsb = (char*)d_ws;
    size_t off = 0;
    auto carve = [&](size_t nbytes) {
        void* p = wsb + off;
        off += (nbytes + 255) & ~(size_t)255;
        return p;
    };
    const size_t NB = (size_t)NITEMS * BATCH;
    const size_t NEU = (size_t)NBUCKU * CAPU;
    const size_t NEI = (size_t)NBUCKI * CAPI;
    float*  tauA   = (float*)carve(NB * 4);
    float*  tauB   = (float*)carve(NB * 4);
    __half* tauHall = (__half*)carve((ORDER + 1) * SLOT * 2);
    Half4*  ybuf   = (Half4*)carve(((size_t)NUSERS + 1) * BATCH * 2);
    int*    uptr   = (int*)carve(NUSERS * 4);
    int*    iptr   = (int*)carve(NITEMS * 4);
    int*    udeg   = (int*)carve(NUSERS * 4);
    int*    ideg   = (int*)carve(NITEMS * 4);
    int*    bcurU  = (int*)carve(NBUCKU * 4);
    int*    bcurI  = (int*)carve(NBUCKI * 4);
    int*    ucol   = (int*)carve(NEU * 4);
    int*    irow   = (int*)carve(NEI * 4);
    int*    stU    = (int*)tauHall;                // staging aliases tauHall
    int*    stI    = (int*)tauHall + NEU;
    (void)ws_size;

    float c[ORDER + 1];
    cheby_coeffs_host(c);
    Coeffs cf;
    float csum = 0.f;
    for (int k = 0; k <= ORDER; ++k) { cf.v[k] = c[k]; csum += c[k]; }

    // ---- CSR build ----
    init_bcur<<<(NBUCKU + 255) / 256, 256, 0, stream>>>(bcurU, bcurI);
    scatter1<<<S1_BLOCKS, 256, 0, stream>>>(row, col, bcurU, bcurI, stU, stI, nnz);
    scatter2<<<NBUCKU, 256, 0, stream>>>(bcurU, stU, uptr, udeg, ucol, NUSERS, CAPU, NITEMS);
    scatter2<<<NBUCKI, 256, 0, stream>>>(bcurI, stI, iptr, ideg, irow, NITEMS, CAPI, NUSERS);
    zero_pads<<<1, 256, 0, stream>>>(tauHall, (__half*)ybuf);

    // ---- tau0 (fp32 + fp16 slot 0) ----
    dim3 tb(32, 8);
    transpose_scale_k<<<dim3((NITEMS + 31) / 32, (BATCH + 31) / 32), tb, 0, stream>>>(
        signal, ideg, tauA, tauHall);

    const int ug = ((NUSERS / RPW) * 64 + 255) / 256;   // 8 rows/wave
    const int ig = ((NITEMS / RPW) * 64 + 255) / 256;

    // ---- k = 1 ----
    spmm_user<<<ug, 256, 0, stream>>>(uptr, udeg, ucol, (const Half4*)tauHall, ybuf);
    spmm_item_first<<<ig, 256, 0, stream>>>(iptr, ideg, irow, ybuf, tauA, tauB,
                                            (Half4*)(tauHall + SLOT));

    float* t0 = tauA;
    float* t1 = tauB;
    for (int k = 2; k <= ORDER; ++k) {
        spmm_user<<<ug, 256, 0, stream>>>(uptr, udeg, ucol,
                                          (const Half4*)(tauHall + (size_t)(k - 1) * SLOT), ybuf);
        spmm_item_k<<<ig, 256, 0, stream>>>(iptr, ideg, irow, ybuf, t1, t0,
                                            (Half4*)(tauHall + (size_t)k * SLOT));
        float* tmp = t0; t0 = t1; t1 = tmp;
    }

    // ---- d_out = sqrt(di) * sum_k c_k tauH_k, transposed ----
    transpose_out_k<<<dim3((BATCH + 31) / 32, (NITEMS + 31) / 32), tb, 0, stream>>>(
        tauHall, signal, ideg, csum, cf, (float*)d_out);
}

// Round 19
// 768.131 us; speedup vs baseline: 1.2765x; 1.2765x over previous
//
#include <hip/hip_runtime.h>
#include <hip/hip_fp16.h>
#include <math.h>

#define NUSERS 100000
#define NITEMS 50000
#define BATCH  64
#define ORDER  8
#define BSHIFT 9                                   // 512 rows per bucket
#define BROWS  (1 << BSHIFT)
#define NBUCKU ((NUSERS + BROWS - 1) >> BSHIFT)    // 196
#define NBUCKI ((NITEMS + BROWS - 1) >> BSHIFT)    // 98
#define CAPU 16384
#define CAPI 24576
#define S1_BLOCKS 512
#define NREP 4

// ---------------------------------------------------------------------------
// FINAL (R17 revert, best measured 768us):
//   - tau-space reformulation (R6): unweighted neighbor sums, vals[] never
//     read; scales 1/deg, rsqrt inlined.
//   - bucket-binned CSR build (R8/R14): block-aggregated reservations,
//     fixed-capacity buckets, rows padded to mult-16 edges (dummy->zero row).
//   - fp16 gather operands (R10/R11): y and all 9 tau_k fp16; fp32 recurrence
//     state; final transpose computes sum(c_k tau_kH) (R12).
//   - 4 rows/wave both SpMMs (R17): measured MLP optimum (2<4>8; 16B/lane and
//     bin-sort both regressed -- lines/instr width-invariant, imbalance
//     TLP-absorbed, occupancy*inflight maximized at 36 VGPR).
// ---------------------------------------------------------------------------

struct __align__(8) Half4 { __half2 a, b; };
struct Coeffs { float v[ORDER + 1]; };

#define SLOT ((size_t)(NITEMS + 1) * BATCH)        // fp16 tau slot incl. zero row

__device__ __forceinline__ void acc_pk(float4& acc, Half4 v0, Half4 v1,
                                       Half4 v2, Half4 v3) {
    __half2 sa = __hadd2(__hadd2(v0.a, v1.a), __hadd2(v2.a, v3.a));
    __half2 sb = __hadd2(__hadd2(v0.b, v1.b), __hadd2(v2.b, v3.b));
    float2 fa = __half22float2(sa);
    float2 fb = __half22float2(sb);
    acc.x += fa.x; acc.y += fa.y; acc.z += fb.x; acc.w += fb.y;
}

__device__ __forceinline__ Half4 to_h4(float x, float y, float z, float w) {
    Half4 h;
    h.a = __floats2half2_rn(x, y);
    h.b = __floats2half2_rn(z, w);
    return h;
}

// ---------------------------------------------------------------------------
// CSR build
// ---------------------------------------------------------------------------
__global__ void init_bcur(int* __restrict__ bcurU, int* __restrict__ bcurI) {
    int t = blockIdx.x * blockDim.x + threadIdx.x;
    if (t < NBUCKU) bcurU[t] = t * CAPU;
    if (t < NBUCKI) bcurI[t] = t * CAPI;
}

__global__ void zero_pads(__half* __restrict__ tauHall, __half* __restrict__ ybuf) {
    int t = threadIdx.x;
    for (int k = 0; k <= ORDER; ++k)
        if (t < BATCH) tauHall[(size_t)k * SLOT + (size_t)NITEMS * BATCH + t] = __float2half(0.f);
    if (t < BATCH) ybuf[(size_t)NUSERS * BATCH + t] = __float2half(0.f);
}

__global__ void scatter1(const int* __restrict__ row, const int* __restrict__ col,
                         int* __restrict__ bcurU, int* __restrict__ bcurI,
                         int* __restrict__ stU, int* __restrict__ stI, int nnz) {
    __shared__ int cU[NREP][NBUCKU];
    __shared__ int cI[NREP][NBUCKI];
    const int chunk = (nnz + S1_BLOCKS - 1) / S1_BLOCKS;
    const int b0 = blockIdx.x * chunk;
    const int e0 = min(b0 + chunk, nnz);
    const int sw = threadIdx.x >> 6;
    for (int t = threadIdx.x; t < NREP * NBUCKU; t += blockDim.x) (&cU[0][0])[t] = 0;
    for (int t = threadIdx.x; t < NREP * NBUCKI; t += blockDim.x) (&cI[0][0])[t] = 0;
    __syncthreads();
    for (int i = b0 + threadIdx.x; i < e0; i += blockDim.x) {
        atomicAdd(&cU[sw][row[i] >> BSHIFT], 1);
        atomicAdd(&cI[sw][col[i] >> BSHIFT], 1);
    }
    __syncthreads();
    for (int t = threadIdx.x; t < NBUCKU; t += blockDim.x) {
        int c0 = cU[0][t], c1 = cU[1][t], c2 = cU[2][t], c3 = cU[3][t];
        int tot = c0 + c1 + c2 + c3;
        int base = (tot > 0) ? atomicAdd(&bcurU[t], tot) : 0;
        cU[0][t] = base;
        cU[1][t] = base + c0;
        cU[2][t] = base + c0 + c1;
        cU[3][t] = base + c0 + c1 + c2;
    }
    for (int t = threadIdx.x; t < NBUCKI; t += blockDim.x) {
        int c0 = cI[0][t], c1 = cI[1][t], c2 = cI[2][t], c3 = cI[3][t];
        int tot = c0 + c1 + c2 + c3;
        int base = (tot > 0) ? atomicAdd(&bcurI[t], tot) : 0;
        cI[0][t] = base;
        cI[1][t] = base + c0;
        cI[2][t] = base + c0 + c1;
        cI[3][t] = base + c0 + c1 + c2;
    }
    __syncthreads();
    for (int i = b0 + threadIdx.x; i < e0; i += blockDim.x) {
        int r = row[i], c = col[i];
        int pu = atomicAdd(&cU[sw][r >> BSHIFT], 1);
        stU[pu] = ((r & (BROWS - 1)) << 17) | c;
        int pi = atomicAdd(&cI[sw][c >> BSHIFT], 1);
        stI[pi] = ((c & (BROWS - 1)) << 17) | r;
    }
}

__global__ void scatter2(const int* __restrict__ bcur, const int* __restrict__ st,
                         int* __restrict__ ptr, int* __restrict__ degOut,
                         int* __restrict__ outIdx, int nrows, int cap, int dummyIdx) {
    __shared__ int deg[BROWS];
    __shared__ int ps[256];
    __shared__ int cur[BROWS];
    __shared__ int rs[BROWS];
    const int rbase = blockIdx.x << BSHIFT;
    const int nr = min(BROWS, nrows - rbase);
    const int lo = blockIdx.x * cap;
    const int hi = bcur[blockIdx.x];
    const int t = threadIdx.x;
    deg[2 * t] = 0;
    deg[2 * t + 1] = 0;
    __syncthreads();
    for (int j = lo + t; j < hi; j += 256)
        atomicAdd(&deg[st[j] >> 17], 1);
    __syncthreads();
    int a = deg[2 * t];
    int b = deg[2 * t + 1];
    int pa = (a + 15) & ~15;
    int pb = (b + 15) & ~15;
    ps[t] = pa + pb;
    __syncthreads();
    for (int off = 1; off < 256; off <<= 1) {
        int u = (t >= off) ? ps[t - off] : 0;
        __syncthreads();
        ps[t] += u;
        __syncthreads();
    }
    int excl = (t > 0) ? ps[t - 1] : 0;
    int p0 = lo + excl;
    int p1 = p0 + pa;
    rs[2 * t] = p0;
    rs[2 * t + 1] = p1;
    cur[2 * t] = p0;
    cur[2 * t + 1] = p1;
    if (2 * t < nr)     { ptr[rbase + 2 * t] = p0;     degOut[rbase + 2 * t] = a; }
    if (2 * t + 1 < nr) { ptr[rbase + 2 * t + 1] = p1; degOut[rbase + 2 * t + 1] = b; }
    __syncthreads();
    for (int j = lo + t; j < hi; j += 256) {
        int v = st[j];
        int p = atomicAdd(&cur[v >> 17], 1);
        outIdx[p] = v & 0x1FFFF;
    }
    __syncthreads();
    for (int i = t; i < nr; i += 256) {
        int endReal = cur[i];
        int endPad  = rs[i] + ((deg[i] + 15) & ~15);
        for (int j = endReal; j < endPad; ++j) outIdx[j] = dummyIdx;
    }
}

// ---------------------------------------------------------------------------
// transposes
// ---------------------------------------------------------------------------
__global__ void transpose_scale_k(const float* __restrict__ in,
                                  const int* __restrict__ ideg,
                                  float* __restrict__ out,
                                  __half* __restrict__ outH) {
    __shared__ float tile[32][33];
    const int cb = blockIdx.x * 32;
    const int rb = blockIdx.y * 32;
    for (int i = threadIdx.y; i < 32; i += 8) {
        int r = rb + i, c = cb + threadIdx.x;
        if (r < BATCH && c < NITEMS) tile[i][threadIdx.x] = in[(size_t)r * NITEMS + c];
    }
    __syncthreads();
    for (int i = threadIdx.y; i < 32; i += 8) {
        int c = cb + i, r = rb + threadIdx.x;
        if (c < NITEMS && r < BATCH) {
            int d = ideg[c];
            float dis = (d > 0) ? rsqrtf((float)d) : 0.0f;
            float v = dis * tile[threadIdx.x][i];
            out[(size_t)c * BATCH + r] = v;
            outH[(size_t)c * BATCH + r] = __float2half(v);
        }
    }
}

__global__ void transpose_out_k(const __half* __restrict__ tauHall,
                                const float* __restrict__ signal,
                                const int* __restrict__ ideg, float csum, Coeffs cf,
                                float* __restrict__ out) {
    __shared__ float tile[32][33];
    const int cb = blockIdx.x * 32;
    const int rb = blockIdx.y * 32;
    for (int i = threadIdx.y; i < 32; i += 8) {
        int r = rb + i, c = cb + threadIdx.x;
        if (r < NITEMS && c < BATCH) {
            size_t base = (size_t)r * BATCH + c;
            float s = 0.f;
            #pragma unroll
            for (int k = 0; k <= ORDER; ++k)
                s += cf.v[k] * __half2float(tauHall[(size_t)k * SLOT + base]);
            tile[i][threadIdx.x] = s;
        }
    }
    __syncthreads();
    for (int i = threadIdx.y; i < 32; i += 8) {
        int c = cb + i, r = rb + threadIdx.x;
        if (c < BATCH && r < NITEMS) {
            int d = ideg[r];
            float v = (d > 0) ? sqrtf((float)d) * tile[threadIdx.x][i]
                              : csum * signal[(size_t)c * NITEMS + r];
            out[(size_t)c * NITEMS + r] = v;
        }
    }
}

// ---------------------------------------------------------------------------
// 4-row gather core: padded rows, exactly n=(deg+15)>>4 iters, 16 gathers in
// flight per wave. Measured MLP optimum.
// ---------------------------------------------------------------------------
__device__ __forceinline__ void gather4_p(const int* __restrict__ idx,
                                          const Half4* __restrict__ x,
                                          const int* b, const int* n,
                                          int sub, int bh, float4* a) {
    int j[4];
    int nmax = 0;
    #pragma unroll
    for (int q = 0; q < 4; ++q) {
        j[q] = b[q] + (sub << 2);
        nmax = max(nmax, n[q]);
    }
    for (int it = 0; it < nmax; ++it) {
        #pragma unroll
        for (int q = 0; q < 4; ++q) {
            if (it < n[q]) {
                int i0 = idx[j[q]], i1 = idx[j[q] + 1];
                int i2 = idx[j[q] + 2], i3 = idx[j[q] + 3];
                Half4 v0 = x[(size_t)i0 * 16 + bh];
                Half4 v1 = x[(size_t)i1 * 16 + bh];
                Half4 v2 = x[(size_t)i2 * 16 + bh];
                Half4 v3 = x[(size_t)i3 * 16 + bh];
                acc_pk(a[q], v0, v1, v2, v3);
                j[q] += 16;
            }
        }
    }
    #pragma unroll
    for (int q = 0; q < 4; ++q) {
        a[q].x += __shfl_xor(a[q].x, 16); a[q].y += __shfl_xor(a[q].y, 16);
        a[q].z += __shfl_xor(a[q].z, 16); a[q].w += __shfl_xor(a[q].w, 16);
        a[q].x += __shfl_xor(a[q].x, 32); a[q].y += __shfl_xor(a[q].y, 32);
        a[q].z += __shfl_xor(a[q].z, 32); a[q].w += __shfl_xor(a[q].w, 32);
    }
}

// user side (4 rows/wave, padded): y[u] = (1/deg_u) * sum tauH[col]
__global__ void spmm_user(const int* __restrict__ ptr, const int* __restrict__ deg,
                          const int* __restrict__ idx,
                          const Half4* __restrict__ tauH, Half4* __restrict__ y) {
    const int lane = threadIdx.x & 63;
    const int w = (blockIdx.x * blockDim.x + threadIdx.x) >> 6;
    const int H = NUSERS / 4;
    if (w >= H) return;
    int r[4] = {w, w + H, w + 2 * H, w + 3 * H};
    const int sub = lane >> 4;
    const int bh  = lane & 15;
    int b[4], d[4], n[4];
    #pragma unroll
    for (int q = 0; q < 4; ++q) {
        b[q] = ptr[r[q]];
        d[q] = deg[r[q]];
        n[q] = (d[q] + 15) >> 4;
    }
    float4 a[4] = {{0,0,0,0},{0,0,0,0},{0,0,0,0},{0,0,0,0}};
    gather4_p(idx, tauH, b, n, sub, bh, a);
    if (sub == 0) {
        #pragma unroll
        for (int q = 0; q < 4; ++q) {
            float s = (d[q] > 0) ? 1.0f / (float)d[q] : 0.0f;
            y[(size_t)r[q] * 16 + bh] = to_h4(s * a[q].x, s * a[q].y, s * a[q].z, s * a[q].w);
        }
    }
}

// item, first step: tau1 = tau0 - (2/deg)*z ; write fp32 + fp16
__global__ void spmm_item_first(const int* __restrict__ ptr, const int* __restrict__ deg,
                                const int* __restrict__ idx, const Half4* __restrict__ y,
                                const float* __restrict__ tau0, float* __restrict__ tau1,
                                Half4* __restrict__ tauH1) {
    const int lane = threadIdx.x & 63;
    const int w = (blockIdx.x * blockDim.x + threadIdx.x) >> 6;
    const int H = NITEMS / 4;
    if (w >= H) return;
    int r[4] = {w, w + H, w + 2 * H, w + 3 * H};
    const int sub = lane >> 4;
    const int bh  = lane & 15;
    int b[4], d[4], n[4];
    #pragma unroll
    for (int q = 0; q < 4; ++q) {
        b[q] = ptr[r[q]];
        d[q] = deg[r[q]];
        n[q] = (d[q] + 15) >> 4;
    }
    float4 a[4] = {{0,0,0,0},{0,0,0,0},{0,0,0,0},{0,0,0,0}};
    gather4_p(idx, y, b, n, sub, bh, a);
    if (sub == 0) {
        #pragma unroll
        for (int q = 0; q < 4; ++q) {
            float inv = (d[q] > 0) ? 1.0f / (float)d[q] : 0.0f;
            float s2 = 2.0f * inv;
            size_t base = (size_t)r[q] * BATCH + (bh << 2);
            float4 t0v = *(const float4*)&tau0[base];
            float4 t;
            t.x = t0v.x - s2 * a[q].x; t.y = t0v.y - s2 * a[q].y;
            t.z = t0v.z - s2 * a[q].z; t.w = t0v.w - s2 * a[q].w;
            *(float4*)&tau1[base] = t;
            tauH1[(size_t)r[q] * 16 + bh] = to_h4(t.x, t.y, t.z, t.w);
        }
    }
}

// item, general step: t2 = 2*t1 - (4/deg)*z - t0 ; write fp32 + fp16
__global__ void spmm_item_k(const int* __restrict__ ptr, const int* __restrict__ deg,
                            const int* __restrict__ idx, const Half4* __restrict__ y,
                            const float* __restrict__ tau1, float* __restrict__ tau0,
                            Half4* __restrict__ tauHk) {
    const int lane = threadIdx.x & 63;
    const int w = (blockIdx.x * blockDim.x + threadIdx.x) >> 6;
    const int H = NITEMS / 4;
    if (w >= H) return;
    int r[4] = {w, w + H, w + 2 * H, w + 3 * H};
    const int sub = lane >> 4;
    const int bh  = lane & 15;
    int b[4], d[4], n[4];
    #pragma unroll
    for (int q = 0; q < 4; ++q) {
        b[q] = ptr[r[q]];
        d[q] = deg[r[q]];
        n[q] = (d[q] + 15) >> 4;
    }
    float4 a[4] = {{0,0,0,0},{0,0,0,0},{0,0,0,0},{0,0,0,0}};
    gather4_p(idx, y, b, n, sub, bh, a);
    if (sub == 0) {
        #pragma unroll
        for (int q = 0; q < 4; ++q) {
            float inv = (d[q] > 0) ? 1.0f / (float)d[q] : 0.0f;
            float s4 = 4.0f * inv;
            size_t base = (size_t)r[q] * BATCH + (bh << 2);
            float4 t1v = *(const float4*)&tau1[base];
            float4 t0v = *(const float4*)&tau0[base];
            float4 t2;
            t2.x = 2.0f * t1v.x - s4 * a[q].x - t0v.x;
            t2.y = 2.0f * t1v.y - s4 * a[q].y - t0v.y;
            t2.z = 2.0f * t1v.z - s4 * a[q].z - t0v.z;
            t2.w = 2.0f * t1v.w - s4 * a[q].w - t0v.w;
            *(float4*)&tau0[base] = t2;
            tauHk[(size_t)r[q] * 16 + bh] = to_h4(t2.x, t2.y, t2.z, t2.w);
        }
    }
}

// ---------------------------------------------------------------------------
// Host-side exact replica of reference cheby_coeffs
// ---------------------------------------------------------------------------
static void cheby_coeffs_host(float* c) {
    const int order = ORDER, flatness = 2;
    const double PI = 3.14159265358979323846;
    double tgt[ORDER + 1], nodes[ORDER + 1];
    for (int x = 0; x <= order; ++x) {
        double xv = cos((double)(order - x) / order * PI);
        xv = nearbyint(xv * 1000.0) / 1000.0;
        double t = (xv < 0.0) ? pow(-xv, (double)flatness) * 0.5 + 0.5
                              : pow(xv, (double)flatness) * (-0.5) + 0.5;
        tgt[x] = nearbyint(t * 1000.0) / 1000.0;
    }
    for (int k = 1; k <= order + 1; ++k)
        nodes[k - 1] = cos((order + 1 + 0.5 - k) / (double)(order + 1) * PI);

    double prev[ORDER + 1], cur[ORDER + 1], nxt[ORDER + 1];
    double sums[ORDER + 1];
    double s0 = 0, s1 = 0;
    for (int i = 0; i <= order; ++i) {
        prev[i] = tgt[i];
        cur[i]  = nodes[i] * tgt[i];
        s0 += prev[i];
        s1 += cur[i];
    }
    sums[0] = s0; sums[1] = s1;
    for (int j = 2; j <= order; ++j) {
        double s = 0;
        for (int i = 0; i <= order; ++i) {
            nxt[i] = nodes[i] * cur[i] * 2.0 - prev[i];
            s += nxt[i];
        }
        sums[j] = s;
        for (int i = 0; i <= order; ++i) { prev[i] = cur[i]; cur[i] = nxt[i]; }
    }
    for (int j = 0; j <= order; ++j)
        c[j] = (float)(sums[j] * (2.0 / (order + 1)));
    c[0] *= 0.5f;
}

extern "C" void kernel_launch(void* const* d_in, const int* in_sizes, int n_in,
                              void* d_out, int out_size, void* d_ws, size_t ws_size,
                              hipStream_t stream) {
    const float* signal = (const float*)d_in[0];   // [BATCH, NITEMS]
    const int*   row    = (const int*)d_in[2];     // [NNZ] -> users
    const int*   col    = (const int*)d_in[3];     // [NNZ] -> items
    const int nnz = in_sizes[1];

    char* wsb = (char*)d_ws;
    size_t off = 0;
    auto carve = [&](size_t nbytes) {
        void* p = wsb + off;
        off += (nbytes + 255) & ~(size_t)255;
        return p;
    };
    const size_t NB = (size_t)NITEMS * BATCH;
    const size_t NEU = (size_t)NBUCKU * CAPU;
    const size_t NEI = (size_t)NBUCKI * CAPI;
    float*  tauA   = (float*)carve(NB * 4);
    float*  tauB   = (float*)carve(NB * 4);
    __half* tauHall = (__half*)carve((ORDER + 1) * SLOT * 2);
    Half4*  ybuf   = (Half4*)carve(((size_t)NUSERS + 1) * BATCH * 2);
    int*    uptr   = (int*)carve(NUSERS * 4);
    int*    iptr   = (int*)carve(NITEMS * 4);
    int*    udeg   = (int*)carve(NUSERS * 4);
    int*    ideg   = (int*)carve(NITEMS * 4);
    int*    bcurU  = (int*)carve(NBUCKU * 4);
    int*    bcurI  = (int*)carve(NBUCKI * 4);
    int*    ucol   = (int*)carve(NEU * 4);
    int*    irow   = (int*)carve(NEI * 4);
    int*    stU    = (int*)tauHall;                // staging aliases tauHall
    int*    stI    = (int*)tauHall + NEU;
    (void)ws_size;

    float c[ORDER + 1];
    cheby_coeffs_host(c);
    Coeffs cf;
    float csum = 0.f;
    for (int k = 0; k <= ORDER; ++k) { cf.v[k] = c[k]; csum += c[k]; }

    // ---- CSR build ----
    init_bcur<<<(NBUCKU + 255) / 256, 256, 0, stream>>>(bcurU, bcurI);
    scatter1<<<S1_BLOCKS, 256, 0, stream>>>(row, col, bcurU, bcurI, stU, stI, nnz);
    scatter2<<<NBUCKU, 256, 0, stream>>>(bcurU, stU, uptr, udeg, ucol, NUSERS, CAPU, NITEMS);
    scatter2<<<NBUCKI, 256, 0, stream>>>(bcurI, stI, iptr, ideg, irow, NITEMS, CAPI, NUSERS);
    zero_pads<<<1, 256, 0, stream>>>(tauHall, (__half*)ybuf);

    // ---- tau0 (fp32 + fp16 slot 0) ----
    dim3 tb(32, 8);
    transpose_scale_k<<<dim3((NITEMS + 31) / 32, (BATCH + 31) / 32), tb, 0, stream>>>(
        signal, ideg, tauA, tauHall);

    const int ug = ((NUSERS / 4) * 64 + 255) / 256;   // 4 rows/wave
    const int ig = ((NITEMS / 4) * 64 + 255) / 256;

    // ---- k = 1 ----
    spmm_user<<<ug, 256, 0, stream>>>(uptr, udeg, ucol, (const Half4*)tauHall, ybuf);
    spmm_item_first<<<ig, 256, 0, stream>>>(iptr, ideg, irow, ybuf, tauA, tauB,
                                            (Half4*)(tauHall + SLOT));

    float* t0 = tauA;
    float* t1 = tauB;
    for (int k = 2; k <= ORDER; ++k) {
        spmm_user<<<ug, 256, 0, stream>>>(uptr, udeg, ucol,
                                          (const Half4*)(tauHall + (size_t)(k - 1) * SLOT), ybuf);
        spmm_item_k<<<ig, 256, 0, stream>>>(iptr, ideg, irow, ybuf, t1, t0,
                                            (Half4*)(tauHall + (size_t)k * SLOT));
        float* tmp = t0; t0 = t1; t1 = tmp;
    }

    // ---- d_out = sqrt(di) * sum_k c_k tauH_k, transposed ----
    transpose_out_k<<<dim3((BATCH + 31) / 32, (NITEMS + 31) / 32), tb, 0, stream>>>(
        tauHall, signal, ideg, csum, cf, (float*)d_out);
}